// Round 11
// baseline (210.351 us; speedup 1.0000x reference)
//
#include <hip/hip_runtime.h>

#define LRELU_ALPHA 0.2f

typedef __bf16 bf16x8 __attribute__((ext_vector_type(8)));
typedef unsigned short u16;
typedef unsigned short u16x8 __attribute__((ext_vector_type(8)));
typedef float f32x4 __attribute__((ext_vector_type(4)));
typedef float f32x16 __attribute__((ext_vector_type(16)));
typedef int int4v __attribute__((ext_vector_type(4)));
typedef unsigned int u32;
typedef unsigned int u32x4 __attribute__((ext_vector_type(4)));
typedef unsigned long long u64;

__device__ __forceinline__ u16 f2bf(float f) {
  unsigned int u = __float_as_uint(f);
  u += 0x7fffu + ((u >> 16) & 1u);   // RNE
  return (u16)(u >> 16);
}

// ---------------- kernel 1: WbT[o][i] = bf16(W[i][o]) ----------------
__global__ __launch_bounds__(256) void wcast(const float* __restrict__ W,
                                             u16* __restrict__ WbT) {
  int idx = blockIdx.x * 256 + threadIdx.x;            // 65536
  WbT[idx] = f2bf(W[(idx & 255) * 256 + (idx >> 8)]);
}

// ---------------- kernel 2: Hh = bf16(h) @ W, fused s/d dots ----------
// NEW HhTt layout for 32x32x16 B-frags (u16 index):
// b*2^20 + (kk>>4)*4096 + (col>>5)*512 + (col&31)*16 + (kk&15)
// => each (ktile16, coltile32) is a contiguous 1KB wave-fragment.
__global__ __launch_bounds__(256) void gemm1(const float* __restrict__ h,
                                             const u16* __restrict__ WbT,
                                             const float* __restrict__ a,
                                             u16* __restrict__ HhTt,
                                             float* __restrict__ sbuf,
                                             float* __restrict__ dbuf) {
  const int tid = threadIdx.x, bid = blockIdx.x;
  const int l = tid & 63, w = tid >> 6;
  const int lr = l & 15;
  const int lk = (l >> 4) << 3;
  const int rowA = bid * 64 + 16 * w + lr;
  const float* hrow = h + (size_t)rowA * 256 + lk;

  f32x4 acc[16];
#pragma unroll
  for (int n = 0; n < 16; ++n) acc[n] = (f32x4){0.f, 0.f, 0.f, 0.f};

  for (int k0 = 0; k0 < 256; k0 += 32) {
    f32x4 a0 = *(const f32x4*)(hrow + k0);
    f32x4 a1 = *(const f32x4*)(hrow + k0 + 4);
    u16x8 au;
    au[0] = f2bf(a0[0]); au[1] = f2bf(a0[1]); au[2] = f2bf(a0[2]); au[3] = f2bf(a0[3]);
    au[4] = f2bf(a1[0]); au[5] = f2bf(a1[1]); au[6] = f2bf(a1[2]); au[7] = f2bf(a1[3]);
    bf16x8 af = __builtin_bit_cast(bf16x8, au);
#pragma unroll
    for (int n = 0; n < 16; ++n) {
      int4v bv = *(const int4v*)(WbT + (size_t)(16 * n + lr) * 256 + k0 + lk);
      bf16x8 bf = __builtin_bit_cast(bf16x8, bv);
      acc[n] = __builtin_amdgcn_mfma_f32_16x16x32_bf16(af, bf, acc[n], 0, 0, 0);
    }
  }

  float sp[4] = {0.f, 0.f, 0.f, 0.f}, dp[4] = {0.f, 0.f, 0.f, 0.f};
#pragma unroll
  for (int n = 0; n < 16; ++n) {
    int col = 16 * n + lr;
    float as = a[col];
    float ad = a[256 + col];
#pragma unroll
    for (int rr = 0; rr < 4; ++rr) {
      int row = bid * 64 + 16 * w + ((l >> 4) << 2) + rr;
      int bb = row >> 12, kk = row & 4095;
      float v = acc[n][rr];
      size_t addr = (size_t)bb * 1048576 + (size_t)(kk >> 4) * 4096 +
                    (col >> 5) * 512 + (col & 31) * 16 + (kk & 15);
      HhTt[addr] = f2bf(v);
      sp[rr] += v * as;
      dp[rr] += v * ad;
    }
  }
#pragma unroll
  for (int rr = 0; rr < 4; ++rr) {
#pragma unroll
    for (int off = 1; off < 16; off <<= 1) {
      sp[rr] += __shfl_xor(sp[rr], off);
      dp[rr] += __shfl_xor(dp[rr], off);
    }
  }
  if ((l & 15) == 0) {
#pragma unroll
    for (int rr = 0; rr < 4; ++rr) {
      int row = bid * 64 + 16 * w + ((l >> 4) << 2) + rr;
      sbuf[row] = sp[rr];
      dbuf[row] = dp[rr];
    }
  }
}

// ---------------- kernel 3: fused pack + GAT aggregation --------------
// grid 256 (1/CU), 512 thr / 8 waves; BM=64 x BN=256 per block.
// Phase 1: each wave ballots 8 adj rows -> rotated Mk (adj read ONCE).
// One __syncthreads. Phase 2: free-running 128-step loop, 32x32x16 MFMA
// (half the B-frag L1 traffic), B direct from L2-resident tiled HhTt.
__global__ __launch_bounds__(512, 2) void gat_fused(const int* __restrict__ adj,
                                                    const u16* __restrict__ HhTt,
                                                    const float* __restrict__ s,
                                                    const float* __restrict__ d,
                                                    float* __restrict__ out) {
  __shared__ __align__(16) u32 Mk[64 * 128];   // 32 KB rotated mask panel
  __shared__ __align__(16) float Dl[4096];     // 16 KB

  const int tid = threadIdx.x, bid = blockIdx.x;
  const int xcd = bid & 7;
  const int t = (xcd << 5) | (bid >> 3);       // 0..255 bijective
  const int b = t >> 6;                        // batch -> 2 XCDs
  const int rowbase = (t & 63) << 6;

  const int l = tid & 63, w = tid >> 6;        // 8 waves
  const int wr = w & 1, wc = w >> 1;           // 2 row-halves x 4 col-quads
  const int lc = l & 31, kh8 = l >> 5;         // lane row / k-octet
  const int rowloc = wr * 32 + lc;             // local row 0..63

  // ---- stage d ----
  for (int i = tid; i < 1024; i += 512)
    *(f32x4*)&Dl[i * 4] = *(const f32x4*)(d + b * 4096 + i * 4);

  // ---- phase 1: pack own 8 rows (w*8 .. w*8+7), ballot -> rotated Mk ----
  for (int rr = 0; rr < 8; ++rr) {
    const int rloc = w * 8 + rr;
    const int* arow = adj + ((size_t)(b * 4096 + rowbase + rloc)) * 4096;
#pragma unroll 4
    for (int it = 0; it < 16; ++it) {
      const int* bp = arow + it * 256;
      u64 b0 = __ballot(bp[l] != 0);
      u64 b1 = __ballot(bp[l + 64] != 0);
      u64 b2 = __ballot(bp[l + 128] != 0);
      u64 b3 = __ballot(bp[l + 192] != 0);
      if (l < 8) {
        u64 sA = (l & 4) ? b2 : b0;
        u64 sB = (l & 4) ? b3 : b1;
        u64 sel = (l & 2) ? sB : sA;
        u32 w32 = (u32)(sel >> ((l & 1) * 32));
        int c = it * 8 + l;
        Mk[rloc * 128 + ((c + rloc) & 127)] = w32;
      }
    }
  }
  __syncthreads();   // Mk + Dl visible; the only block-wide barrier

  const float s_row = s[b * 4096 + rowbase + rowloc];

  // B base (bytes): lane's slot inside each 1KB (ktile,coltile) fragment
  const char* bbase = (const char*)HhTt + (size_t)b * 2097152 + wc * 2048 +
                      lc * 32 + kh8 * 16;

  f32x16 acc0 = {0.f}, acc1 = {0.f};
#pragma unroll
  for (int i = 0; i < 16; ++i) { acc0[i] = 0.f; acc1[i] = 0.f; }
  float racc = 0.f;
  const int mkb = rowloc * 128;

  for (int st = 0; st < 128; ++st) {
    const char* bs = bbase + (size_t)st * 16384;
    int4v b00 = *(const int4v*)(bs);                 // kh=0, ct=0
    int4v b01 = *(const int4v*)(bs + 1024);          // kh=0, ct=1
    int4v b10 = *(const int4v*)(bs + 8192);          // kh=1, ct=0
    int4v b11 = *(const int4v*)(bs + 9216);          // kh=1, ct=1

    u32 mword = Mk[mkb + ((st + rowloc) & 127)];
    f32x4 d0 = *(const f32x4*)&Dl[st * 32 + kh8 * 8];
    f32x4 d1 = *(const f32x4*)&Dl[st * 32 + kh8 * 8 + 4];
    f32x4 d2 = *(const f32x4*)&Dl[st * 32 + 16 + kh8 * 8];
    f32x4 d3 = *(const f32x4*)&Dl[st * 32 + 20 + kh8 * 8];

    // e-gen: 8 values per k-half; bit = kh*16 + kh8*8 + j
    u32 m0 = mword >> (kh8 * 8);
    u32 m1 = mword >> (16 + kh8 * 8);
    float e0[8], e1[8];
#pragma unroll
    for (int j = 0; j < 8; ++j) {
      float lgA = s_row + (j < 4 ? d0[j & 3] : d1[j & 3]);
      float tA = fmaxf(lgA, LRELU_ALPHA * lgA);
      float eA = ((m0 >> j) & 1) ? __expf(-tA) : 0.f;
      float lgB = s_row + (j < 4 ? d2[j & 3] : d3[j & 3]);
      float tB = fmaxf(lgB, LRELU_ALPHA * lgB);
      float eB = ((m1 >> j) & 1) ? __expf(-tB) : 0.f;
      racc += eA + eB;
      e0[j] = eA;
      e1[j] = eB;
    }
    u32x4 p0, p1;
    asm("v_cvt_pk_bf16_f32 %0, %1, %2" : "=v"(p0[0]) : "v"(e0[0]), "v"(e0[1]));
    asm("v_cvt_pk_bf16_f32 %0, %1, %2" : "=v"(p0[1]) : "v"(e0[2]), "v"(e0[3]));
    asm("v_cvt_pk_bf16_f32 %0, %1, %2" : "=v"(p0[2]) : "v"(e0[4]), "v"(e0[5]));
    asm("v_cvt_pk_bf16_f32 %0, %1, %2" : "=v"(p0[3]) : "v"(e0[6]), "v"(e0[7]));
    asm("v_cvt_pk_bf16_f32 %0, %1, %2" : "=v"(p1[0]) : "v"(e1[0]), "v"(e1[1]));
    asm("v_cvt_pk_bf16_f32 %0, %1, %2" : "=v"(p1[1]) : "v"(e1[2]), "v"(e1[3]));
    asm("v_cvt_pk_bf16_f32 %0, %1, %2" : "=v"(p1[2]) : "v"(e1[4]), "v"(e1[5]));
    asm("v_cvt_pk_bf16_f32 %0, %1, %2" : "=v"(p1[3]) : "v"(e1[6]), "v"(e1[7]));
    bf16x8 af0 = __builtin_bit_cast(bf16x8, p0);
    bf16x8 af1 = __builtin_bit_cast(bf16x8, p1);

    __builtin_amdgcn_s_setprio(1);
    acc0 = __builtin_amdgcn_mfma_f32_32x32x16_bf16(
        af0, __builtin_bit_cast(bf16x8, b00), acc0, 0, 0, 0);
    acc1 = __builtin_amdgcn_mfma_f32_32x32x16_bf16(
        af0, __builtin_bit_cast(bf16x8, b01), acc1, 0, 0, 0);
    acc0 = __builtin_amdgcn_mfma_f32_32x32x16_bf16(
        af1, __builtin_bit_cast(bf16x8, b10), acc0, 0, 0, 0);
    acc1 = __builtin_amdgcn_mfma_f32_32x32x16_bf16(
        af1, __builtin_bit_cast(bf16x8, b11), acc1, 0, 0, 0);
    __builtin_amdgcn_s_setprio(0);
  }

  // ---- rowsum: lane pair (l, l+32) holds disjoint k-slices of row lc ----
  racc += __shfl_xor(racc, 32);   // lanes 0..31 now hold full rowsum of row lc

  // ---- epilogue: divide + elu + store (C/D: col=l&31, row=(reg&3)+8*(reg>>2)+4*kh8) ----
#pragma unroll
  for (int reg = 0; reg < 16; ++reg) {
    const int rl = (reg & 3) + 8 * (reg >> 2) + 4 * kh8;
    float rsv = __shfl(racc, rl);
    float inv = 1.f / (rsv == 0.f ? 1.f : rsv);
    const size_t grow = (size_t)(b * 4096 + rowbase + wr * 32 + rl);
    float v0 = acc0[reg] * inv;
    float v1 = acc1[reg] * inv;
    out[grow * 256 + wc * 64 + lc] = v0 > 0.f ? v0 : (__expf(v0) - 1.f);
    out[grow * 256 + wc * 64 + 32 + lc] = v1 > 0.f ? v1 : (__expf(v1) - 1.f);
  }
}

extern "C" void kernel_launch(void* const* d_in, const int* in_sizes, int n_in,
                              void* d_out, int out_size, void* d_ws, size_t ws_size,
                              hipStream_t stream) {
  const float* h = (const float*)d_in[0];
  const int* adj = (const int*)d_in[1];
  const float* W = (const float*)d_in[2];
  const float* a = (const float*)d_in[3];
  float* out = (float*)d_out;

  u16* WbT  = (u16*)d_ws;                                  // 128 KB
  u16* HhTt = (u16*)((char*)d_ws + 131072);                // 8 MB
  float* sb = (float*)((char*)d_ws + 131072 + 8388608);    // 64 KB
  float* db = sb + 16384;                                  // 64 KB

  hipLaunchKernelGGL(wcast,     dim3(256), dim3(256), 0, stream, W, WbT);
  hipLaunchKernelGGL(gemm1,     dim3(256), dim3(256), 0, stream, h, WbT, a, HhTt, sb, db);
  hipLaunchKernelGGL(gat_fused, dim3(256), dim3(512), 0, stream, adj, HhTt, sb, db, out);
}

// Round 12
// 180.576 us; speedup vs baseline: 1.1649x; 1.1649x over previous
//
#include <hip/hip_runtime.h>

#define LRELU_ALPHA 0.2f

typedef __bf16 bf16x8 __attribute__((ext_vector_type(8)));
typedef unsigned short u16;
typedef unsigned short u16x8 __attribute__((ext_vector_type(8)));
typedef float f32x4 __attribute__((ext_vector_type(4)));
typedef int int4v __attribute__((ext_vector_type(4)));
typedef unsigned int u32;
typedef unsigned long long u64;

__device__ __forceinline__ u16 f2bf(float f) {
  unsigned int u = __float_as_uint(f);
  u += 0x7fffu + ((u >> 16) & 1u);   // RNE
  return (u16)(u >> 16);
}

// ---------------- kernel 1: WbT[o][i] = bf16(W[i][o]) ----------------
__global__ __launch_bounds__(256) void wcast(const float* __restrict__ W,
                                             u16* __restrict__ WbT) {
  int idx = blockIdx.x * 256 + threadIdx.x;            // 65536
  WbT[idx] = f2bf(W[(idx & 255) * 256 + (idx >> 8)]);
}

// ------- kernel 2: fused gemm1 (blocks 0..255) + packadj (256..4351) --
// gemm1 writes HhTt in the R6-verified tiled layout (u16 index):
// b*2^20 + (kk>>5)*8192 + (col>>4)*512 + ((kk>>3)&3)*128 + (col&15)*8 + (kk&7)
__global__ __launch_bounds__(256) void packgemm(const int* __restrict__ adj,
                                                u32* __restrict__ maskg,
                                                const float* __restrict__ h,
                                                const u16* __restrict__ WbT,
                                                const float* __restrict__ a,
                                                u16* __restrict__ HhTt,
                                                float* __restrict__ sbuf,
                                                float* __restrict__ dbuf) {
  const int tid = threadIdx.x;
  const int l = tid & 63, w = tid >> 6;

  if (blockIdx.x >= 256) {
    // ---- pack: 4 rows per block via ballot (R7-proven) ----
    const size_t row = (size_t)(blockIdx.x - 256) * 4 + w;
    const int* arow = adj + row * 4096;
    u64* mrow = (u64*)(maskg + row * 128);
    for (int it = 0; it < 16; ++it) {
      const int* base = arow + it * 256;
      int v0 = base[l], v1 = base[l + 64], v2 = base[l + 128], v3 = base[l + 192];
      u64 b0 = __ballot(v0 != 0);
      u64 b1 = __ballot(v1 != 0);
      u64 b2 = __ballot(v2 != 0);
      u64 b3 = __ballot(v3 != 0);
      if (l == 0) {
        mrow[it * 4 + 0] = b0;
        mrow[it * 4 + 1] = b1;
        mrow[it * 4 + 2] = b2;
        mrow[it * 4 + 3] = b3;
      }
    }
    return;
  }

  // ---- gemm1 (R8-proven, byte-identical) ----
  const int bid = blockIdx.x;
  const int lr = l & 15;
  const int lk = (l >> 4) << 3;
  const int rowA = bid * 64 + 16 * w + lr;
  const float* hrow = h + (size_t)rowA * 256 + lk;

  f32x4 acc[16];
#pragma unroll
  for (int n = 0; n < 16; ++n) acc[n] = (f32x4){0.f, 0.f, 0.f, 0.f};

  for (int k0 = 0; k0 < 256; k0 += 32) {
    f32x4 a0 = *(const f32x4*)(hrow + k0);
    f32x4 a1 = *(const f32x4*)(hrow + k0 + 4);
    u16x8 au;
    au[0] = f2bf(a0[0]); au[1] = f2bf(a0[1]); au[2] = f2bf(a0[2]); au[3] = f2bf(a0[3]);
    au[4] = f2bf(a1[0]); au[5] = f2bf(a1[1]); au[6] = f2bf(a1[2]); au[7] = f2bf(a1[3]);
    bf16x8 af = __builtin_bit_cast(bf16x8, au);
#pragma unroll
    for (int n = 0; n < 16; ++n) {
      int4v bv = *(const int4v*)(WbT + (size_t)(16 * n + lr) * 256 + k0 + lk);
      bf16x8 bf = __builtin_bit_cast(bf16x8, bv);
      acc[n] = __builtin_amdgcn_mfma_f32_16x16x32_bf16(af, bf, acc[n], 0, 0, 0);
    }
  }

  float sp[4] = {0.f, 0.f, 0.f, 0.f}, dp[4] = {0.f, 0.f, 0.f, 0.f};
#pragma unroll
  for (int n = 0; n < 16; ++n) {
    int col = 16 * n + lr;
    float as = a[col];
    float ad = a[256 + col];
#pragma unroll
    for (int rr = 0; rr < 4; ++rr) {
      int row = bid * 64 + 16 * w + ((l >> 4) << 2) + rr;
      int bb = row >> 12, kk = row & 4095;
      float v = acc[n][rr];
      size_t addr = (size_t)bb * 1048576 + (size_t)(kk >> 5) * 8192 +
                    (col >> 4) * 512 + ((kk >> 3) & 3) * 128 + (col & 15) * 8 +
                    (kk & 7);
      HhTt[addr] = f2bf(v);
      sp[rr] += v * as;
      dp[rr] += v * ad;
    }
  }
#pragma unroll
  for (int rr = 0; rr < 4; ++rr) {
#pragma unroll
    for (int off = 1; off < 16; off <<= 1) {
      sp[rr] += __shfl_xor(sp[rr], off);
      dp[rr] += __shfl_xor(dp[rr], off);
    }
  }
  if ((l & 15) == 0) {
#pragma unroll
    for (int rr = 0; rr < 4; ++rr) {
      int row = bid * 64 + 16 * w + ((l >> 4) << 2) + rr;
      sbuf[row] = sp[rr];
      dbuf[row] = dp[rr];
    }
  }
}

// ---------------- kernel 3: main fused GAT aggregation ----------------
// grid 256 (1/CU), 1024 thr / 16 waves (Occupancy 50%).
// BM=64 x BN=256; wave w = col-tile w*16 (B dup x1, 2MB/CU L2 total).
// e-gen computed ONCE (1024 thr x 2 e/step) into 4-buffer At (stride 40
// u16 -> 2-way bank = free). One raw s_barrier + lgkmcnt(0) per step; B
// loads free-float from L2 with depth-1 register prefetch.
__global__ __launch_bounds__(1024, 4) void gat_main(const u32* __restrict__ maskg,
                                                    const u16* __restrict__ HhTt,
                                                    const float* __restrict__ s,
                                                    const float* __restrict__ d,
                                                    float* __restrict__ out) {
  __shared__ __align__(16) u32 Mk[64 * 128];   // 32 KB rotated mask panel
  __shared__ __align__(16) u16 At[4][2560];    // 20 KB: [buf][row64][k32+pad8]
  __shared__ float rs_lds[64];

  const int tid = threadIdx.x, bid = blockIdx.x;
  const int xcd = bid & 7;
  const int t = (xcd << 5) | (bid >> 3);       // 0..255 bijective
  const int b = t >> 6;                        // batch -> 2 XCDs
  const int rowbase = (t & 63) << 6;

  const int l = tid & 63, w = tid >> 6;        // w 0..15 = col-tile
  const int lr = l & 15, lkg = l >> 4;
  const int r = tid >> 4, kp = tid & 15;       // e-gen: row r, k-pair kp

  // ---- stage rotated mask panel: thread covers (row r, words kp*8..+7) ----
  {
    const u32* mrow = maskg + ((size_t)(b * 4096 + rowbase)) * 128;
    const int c0 = kp * 8;
#pragma unroll
    for (int j = 0; j < 8; ++j) {
      int c = c0 + j;
      Mk[r * 128 + ((c + r) & 127)] = mrow[r * 128 + c];
    }
  }
  const float s_r = s[b * 4096 + rowbase + r];
  const float* dtp = d + b * 4096 + kp * 2;    // 8B per step, L1-resident

  float racc = 0.f;

#define EGEN(BUF, STE)                                                        \
  {                                                                           \
    u32 mword = Mk[r * 128 + (((STE) + r) & 127)];                            \
    u32 mb = mword >> (kp * 2);                                               \
    float2 dv = *(const float2*)(dtp + (STE) * 32);                           \
    float lg0 = s_r + dv.x;                                                   \
    float t0 = fmaxf(lg0, LRELU_ALPHA * lg0);                                 \
    float e0 = (mb & 1u) ? __expf(-t0) : 0.f;                                 \
    float lg1 = s_r + dv.y;                                                   \
    float t1 = fmaxf(lg1, LRELU_ALPHA * lg1);                                 \
    float e1 = (mb & 2u) ? __expf(-t1) : 0.f;                                 \
    racc += e0 + e1;                                                          \
    u32 pk;                                                                   \
    asm("v_cvt_pk_bf16_f32 %0, %1, %2" : "=v"(pk) : "v"(e0), "v"(e1));        \
    *(u32*)&At[BUF][r * 40 + kp * 2] = pk;                                    \
  }

  __syncthreads();   // Mk visible (full drain once, prologue only)
  EGEN(0, 0)

  // B source: R6-proven 1KB-contiguous wave fragment
  const char* bbase = (const char*)HhTt + (size_t)b * 2097152 + w * 1024 + l * 16;
  int4v Bcur = *(const int4v*)(bbase);

  f32x4 acc[4];
#pragma unroll
  for (int n = 0; n < 4; ++n) acc[n] = (f32x4){0.f, 0.f, 0.f, 0.f};

  for (int st = 0; st < 128; ++st) {
    if (st < 127) EGEN((st + 1) & 3, st + 1)
    const int pst = (st < 127) ? st + 1 : st;
    int4v Bnext = *(const int4v*)(bbase + (size_t)pst * 16384);

    asm volatile("s_waitcnt lgkmcnt(0)" ::: "memory");
    __builtin_amdgcn_s_barrier();
    __builtin_amdgcn_sched_barrier(0);

    const u16* atb = &At[st & 3][0];
    int4v a0 = *(const int4v*)(atb + (0 * 16 + lr) * 40 + lkg * 8);
    int4v a1 = *(const int4v*)(atb + (1 * 16 + lr) * 40 + lkg * 8);
    int4v a2 = *(const int4v*)(atb + (2 * 16 + lr) * 40 + lkg * 8);
    int4v a3 = *(const int4v*)(atb + (3 * 16 + lr) * 40 + lkg * 8);
    bf16x8 bfv = __builtin_bit_cast(bf16x8, Bcur);
    __builtin_amdgcn_s_setprio(1);
    acc[0] = __builtin_amdgcn_mfma_f32_16x16x32_bf16(
        __builtin_bit_cast(bf16x8, a0), bfv, acc[0], 0, 0, 0);
    acc[1] = __builtin_amdgcn_mfma_f32_16x16x32_bf16(
        __builtin_bit_cast(bf16x8, a1), bfv, acc[1], 0, 0, 0);
    acc[2] = __builtin_amdgcn_mfma_f32_16x16x32_bf16(
        __builtin_bit_cast(bf16x8, a2), bfv, acc[2], 0, 0, 0);
    acc[3] = __builtin_amdgcn_mfma_f32_16x16x32_bf16(
        __builtin_bit_cast(bf16x8, a3), bfv, acc[3], 0, 0, 0);
    __builtin_amdgcn_s_setprio(0);
    Bcur = Bnext;
  }
#undef EGEN

  // ---- rowsum: 16 kp-partials per row live in one 16-lane group ----
  racc += __shfl_xor(racc, 1);
  racc += __shfl_xor(racc, 2);
  racc += __shfl_xor(racc, 4);
  racc += __shfl_xor(racc, 8);
  if (kp == 0) rs_lds[r] = (racc == 0.f) ? 1.f : racc;
  __syncthreads();

  // ---- epilogue: divide + elu + store (C/D: col=l&15, row=(l>>4)*4+reg) ----
#pragma unroll
  for (int rt = 0; rt < 4; ++rt) {
#pragma unroll
    for (int reg = 0; reg < 4; ++reg) {
      int rloc = rt * 16 + lkg * 4 + reg;
      float rsv = rs_lds[rloc];
      float v = acc[rt][reg] / rsv;
      out[((size_t)(b * 4096 + rowbase + rloc)) * 256 + w * 16 + lr] =
          v > 0.f ? v : (__expf(v) - 1.f);
    }
  }
}

extern "C" void kernel_launch(void* const* d_in, const int* in_sizes, int n_in,
                              void* d_out, int out_size, void* d_ws, size_t ws_size,
                              hipStream_t stream) {
  const float* h = (const float*)d_in[0];
  const int* adj = (const int*)d_in[1];
  const float* W = (const float*)d_in[2];
  const float* a = (const float*)d_in[3];
  float* out = (float*)d_out;

  u16* WbT   = (u16*)d_ws;                                       // 128 KB
  u16* HhTt  = (u16*)((char*)d_ws + 131072);                     // 8 MB
  float* sb  = (float*)((char*)d_ws + 131072 + 8388608);         // 64 KB
  float* db  = sb + 16384;                                       // 64 KB
  u32* maskg = (u32*)((char*)d_ws + 131072 + 8388608 + 131072);  // 8 MB

  hipLaunchKernelGGL(wcast,    dim3(256),  dim3(256),  0, stream, W, WbT);
  hipLaunchKernelGGL(packgemm, dim3(4352), dim3(256),  0, stream,
                     adj, maskg, h, WbT, a, HhTt, sb, db);
  hipLaunchKernelGGL(gat_main, dim3(256),  dim3(1024), 0, stream,
                     maskg, HhTt, sb, db, out);
}